// Round 1
// baseline (957.721 us; speedup 1.0000x reference)
//
#include <hip/hip_runtime.h>

#define NN 100000
#define NE 1600000
#define IN_DIM 32
#define DD 64
#define NG 128
#define BN_EPS 1e-5f

// ---------------- utility ----------------
__global__ void fill_f32(float* __restrict__ p, long n, float v) {
    long i = (long)blockIdx.x * blockDim.x + threadIdx.x;
    if (i < n) p[i] = v;
}

__global__ void deg_count(const int* __restrict__ dst, float* __restrict__ deg) {
    int e = blockIdx.x * blockDim.x + threadIdx.x;
    if (e < NE) atomicAdd(&deg[dst[e]], 1.0f);
}

__global__ void rsqrt_k(float* __restrict__ deg) {
    int i = blockIdx.x * blockDim.x + threadIdx.x;
    if (i < NN) deg[i] = rsqrtf(deg[i]);
}

// ---------------- h = x @ W_embed  (N x 32 @ 32 x 64) ----------------
__global__ __launch_bounds__(256) void embed_mm(const float* __restrict__ x,
                                                const float* __restrict__ W,
                                                float* __restrict__ h) {
    __shared__ float Ws[IN_DIM * DD];
    int t = threadIdx.x;
    for (int i = t; i < IN_DIM * DD; i += 256) Ws[i] = W[i];
    __syncthreads();
    long n = (long)blockIdx.x * 256 + t;
    if (n >= NN) return;
    float acc[DD];
#pragma unroll
    for (int d = 0; d < DD; ++d) acc[d] = 0.f;
    const float4* xr = (const float4*)(x + n * IN_DIM);
#pragma unroll
    for (int k4 = 0; k4 < IN_DIM / 4; ++k4) {
        float4 xv = xr[k4];
        const float* xp = (const float*)&xv;
#pragma unroll
        for (int kk = 0; kk < 4; ++kk) {
            float v = xp[kk];
            int k = k4 * 4 + kk;
#pragma unroll
            for (int d = 0; d < DD; ++d) acc[d] += v * Ws[k * DD + d];
        }
    }
    float4* o = (float4*)(h + n * DD);
#pragma unroll
    for (int d4 = 0; d4 < DD / 4; ++d4)
        o[d4] = make_float4(acc[4 * d4], acc[4 * d4 + 1], acc[4 * d4 + 2], acc[4 * d4 + 3]);
}

// ---------------- out = h @ W  (N x 64 @ 64 x 64) ----------------
__global__ __launch_bounds__(256) void lin_mm(const float* __restrict__ h,
                                              const float* __restrict__ W,
                                              float* __restrict__ out) {
    __shared__ float Ws[DD * DD];
    int t = threadIdx.x;
    for (int i = t; i < DD * DD; i += 256) Ws[i] = W[i];
    __syncthreads();
    long n = (long)blockIdx.x * 256 + t;
    if (n >= NN) return;
    float acc[DD];
#pragma unroll
    for (int d = 0; d < DD; ++d) acc[d] = 0.f;
    const float4* hr = (const float4*)(h + n * DD);
#pragma unroll
    for (int k4 = 0; k4 < DD / 4; ++k4) {
        float4 hv = hr[k4];
        const float* hp = (const float*)&hv;
#pragma unroll
        for (int kk = 0; kk < 4; ++kk) {
            float v = hp[kk];
            int k = k4 * 4 + kk;
#pragma unroll
            for (int d = 0; d < DD; ++d) acc[d] += v * Ws[k * DD + d];
        }
    }
    float4* o = (float4*)(out + n * DD);
#pragma unroll
    for (int d4 = 0; d4 < DD / 4; ++d4)
        o[d4] = make_float4(acc[4 * d4], acc[4 * d4 + 1], acc[4 * d4 + 2], acc[4 * d4 + 3]);
}

// ---------------- agg = hw * self_norm + b ----------------
__global__ void self_init(const float* __restrict__ hw, const float* __restrict__ dis,
                          const float* __restrict__ b, float* __restrict__ agg) {
    long i = (long)blockIdx.x * blockDim.x + threadIdx.x;
    if (i >= (long)NN * DD) return;
    long n = i >> 6;
    int d = (int)(i & 63);
    float s = dis[n];
    agg[i] = hw[i] * (s * s) + b[d];
}

// ---------------- edge scatter: agg[dst] += hw[src] * enorm ----------------
__global__ void scatter_k(const float* __restrict__ hw, const int* __restrict__ src,
                          const int* __restrict__ dst, const float* __restrict__ dis,
                          float* __restrict__ agg) {
    long gid = (long)blockIdx.x * blockDim.x + threadIdx.x;
    if (gid >= (long)NE * DD) return;
    long e = gid >> 6;
    int d = (int)(gid & 63);
    int s = src[e];
    int t = dst[e];
    float norm = dis[s] * dis[t];
    atomicAdd(&agg[(long)t * DD + d], hw[(long)s * DD + d] * norm);
}

// ---------------- BN stats: per-channel sum + sumsq ----------------
__global__ __launch_bounds__(256) void bn_stats(const float* __restrict__ agg,
                                                float* __restrict__ sums) {
    __shared__ float ls[256], ls2[256];
    int t = threadIdx.x;
    long stride = (long)gridDim.x * 256;  // multiple of 64 -> channel stays fixed
    float s = 0.f, s2 = 0.f;
    for (long i = (long)blockIdx.x * 256 + t; i < (long)NN * DD; i += stride) {
        float v = agg[i];
        s += v;
        s2 += v * v;
    }
    ls[t] = s;
    ls2[t] = s2;
    __syncthreads();
    if (t < 64) {
        s = ls[t] + ls[t + 64] + ls[t + 128] + ls[t + 192];
        s2 = ls2[t] + ls2[t + 64] + ls2[t + 128] + ls2[t + 192];
        atomicAdd(&sums[t], s);
        atomicAdd(&sums[64 + t], s2);
    }
}

// ---------------- BN apply (+optional ReLU) ----------------
__global__ void bn_apply(const float* __restrict__ agg, const float* __restrict__ sums,
                         const float* __restrict__ g, const float* __restrict__ bt,
                         float* __restrict__ out, int relu) {
    long i = (long)blockIdx.x * blockDim.x + threadIdx.x;
    if (i >= (long)NN * DD) return;
    int d = (int)(i & 63);
    const float inv_n = 1.0f / (float)NN;
    float mu = sums[d] * inv_n;
    float var = sums[64 + d] * inv_n - mu * mu;
    float sc = g[d] * rsqrtf(var + BN_EPS);
    float v = (agg[i] - mu) * sc + bt[d];
    if (relu) v = fmaxf(v, 0.f);
    out[i] = v;
}

// ---------------- pool: batch is sorted -> run-length + flush ----------------
__global__ __launch_bounds__(256) void pool_k(const float* __restrict__ h,
                                              const int* __restrict__ batch,
                                              float* __restrict__ pool) {
    const int ROWS = 256;  // rows per block
    int t = threadIdx.x;
    int d = t & 63;
    int rq = t >> 6;  // 0..3
    long base = (long)blockIdx.x * ROWS;
    float acc = 0.f;
    int cur = -1;
    for (int i = 0; i < ROWS / 4; ++i) {
        long r = base + rq + 4 * i;
        if (r >= NN) break;
        int b = batch[r];
        float v = h[r * DD + d];
        if (b != cur) {
            if (cur >= 0) atomicAdd(&pool[(long)cur * DD + d], acc);
            acc = 0.f;
            cur = b;
        }
        acc += v;
    }
    if (cur >= 0) atomicAdd(&pool[(long)cur * DD + d], acc);
}

extern "C" void kernel_launch(void* const* d_in, const int* in_sizes, int n_in,
                              void* d_out, int out_size, void* d_ws, size_t ws_size,
                              hipStream_t stream) {
    const float* x = (const float*)d_in[0];
    const int* ei = (const int*)d_in[1];
    const int* batch = (const int*)d_in[2];
    const float* W_embed = (const float*)d_in[3];
    const float* W1 = (const float*)d_in[4];
    const float* b1 = (const float*)d_in[5];
    const float* g1 = (const float*)d_in[6];
    const float* bt1 = (const float*)d_in[7];
    const float* W2 = (const float*)d_in[8];
    const float* b2 = (const float*)d_in[9];
    const float* g2 = (const float*)d_in[10];
    const float* bt2 = (const float*)d_in[11];

    const int* src = ei;
    const int* dst = ei + NE;

    float* out = (float*)d_out;           // h: N*DD floats
    float* pool = out + (long)NN * DD;    // h_pool: NG*DD floats

    float* ws = (float*)d_ws;
    float* deg = ws;                      // N floats (becomes dis)
    float* sums = ws + NN;                // 128 floats
    float* A = sums + 128;                // N*DD
    float* B = A + (long)NN * DD;         // N*DD
    float* C = B + (long)NN * DD;         // N*DD

    const long ND = (long)NN * DD;
    const long ED = (long)NE * DD;
    dim3 blk(256);

    // degree + norms
    fill_f32<<<dim3((NN + 255) / 256), blk, 0, stream>>>(deg, NN, 1.0f);
    fill_f32<<<dim3((NG * DD + 255) / 256), blk, 0, stream>>>(pool, (long)NG * DD, 0.0f);
    deg_count<<<dim3((NE + 255) / 256), blk, 0, stream>>>(dst, deg);
    rsqrt_k<<<dim3((NN + 255) / 256), blk, 0, stream>>>(deg);  // deg -> dis in place

    // embed
    embed_mm<<<dim3((NN + 255) / 256), blk, 0, stream>>>(x, W_embed, A);

    // ---- layer 1: A -> C (relu) ----
    lin_mm<<<dim3((NN + 255) / 256), blk, 0, stream>>>(A, W1, B);
    self_init<<<dim3((int)((ND + 255) / 256)), blk, 0, stream>>>(B, deg, b1, C);
    scatter_k<<<dim3((int)((ED + 255) / 256)), blk, 0, stream>>>(B, src, dst, deg, C);
    fill_f32<<<dim3(1), blk, 0, stream>>>(sums, 128, 0.0f);
    bn_stats<<<dim3(512), blk, 0, stream>>>(C, sums);
    bn_apply<<<dim3((int)((ND + 255) / 256)), blk, 0, stream>>>(C, sums, g1, bt1, C, 1);

    // ---- layer 2: C -> d_out (no relu) ----
    lin_mm<<<dim3((NN + 255) / 256), blk, 0, stream>>>(C, W2, B);
    self_init<<<dim3((int)((ND + 255) / 256)), blk, 0, stream>>>(B, deg, b2, A);
    scatter_k<<<dim3((int)((ED + 255) / 256)), blk, 0, stream>>>(B, src, dst, deg, A);
    fill_f32<<<dim3(1), blk, 0, stream>>>(sums, 128, 0.0f);
    bn_stats<<<dim3(512), blk, 0, stream>>>(A, sums);
    bn_apply<<<dim3((int)((ND + 255) / 256)), blk, 0, stream>>>(A, sums, g2, bt2, out, 0);

    // ---- pool ----
    pool_k<<<dim3((NN + 255) / 256), blk, 0, stream>>>(out, batch, pool);
}

// Round 2
// 672.089 us; speedup vs baseline: 1.4250x; 1.4250x over previous
//
#include <hip/hip_runtime.h>

#define NN 100000
#define NE 1600000
#define IN_DIM 32
#define DD 64
#define NG 128
#define BN_EPS 1e-5f
#define AGG_BLOCKS 2048

// ---------------- utility ----------------
__global__ void zero_i32(int* __restrict__ p, long n) {
    long i = (long)blockIdx.x * blockDim.x + threadIdx.x;
    if (i < n) p[i] = 0;
}

__global__ void deg_count(const int* __restrict__ dst, int* __restrict__ cnt) {
    int e = blockIdx.x * blockDim.x + threadIdx.x;
    if (e < NE) atomicAdd(&cnt[dst[e]], 1);
}

__global__ void dis_k(const int* __restrict__ cnt, float* __restrict__ dis) {
    int i = blockIdx.x * blockDim.x + threadIdx.x;
    if (i < NN) dis[i] = rsqrtf((float)cnt[i] + 1.0f);
}

// Range allocation: start[n] = exclusive-prefix within block + atomic block base.
// (Node ranges land in nondeterministic global order, but each node's range is
// contiguous, which is all the gather kernel needs.)
__global__ __launch_bounds__(256) void alloc_k(const int* __restrict__ cnt,
                                               int* __restrict__ start,
                                               int* __restrict__ cursor) {
    __shared__ int ls[256];
    __shared__ int base_s;
    int t = threadIdx.x;
    long n = (long)blockIdx.x * 256 + t;
    int v = (n < NN) ? cnt[n] : 0;
    ls[t] = v;
    __syncthreads();
    for (int off = 1; off < 256; off <<= 1) {
        int y = (t >= off) ? ls[t - off] : 0;
        __syncthreads();
        ls[t] += y;
        __syncthreads();
    }
    if (t == 0) base_s = atomicAdd(cursor, ls[255]);
    __syncthreads();
    if (n < NN) start[n] = base_s + ls[t] - v;
}

// Bucket fill: epack[slot] = {src, enorm}
__global__ void fill_edges(const int* __restrict__ src, const int* __restrict__ dstp,
                           const float* __restrict__ dis, const int* __restrict__ start,
                           int* __restrict__ cur, int2* __restrict__ epack) {
    int e = blockIdx.x * blockDim.x + threadIdx.x;
    if (e >= NE) return;
    int s = src[e], t = dstp[e];
    int p = atomicAdd(&cur[t], 1);
    float nm = dis[s] * dis[t];
    epack[start[t] + p] = make_int2(s, __float_as_int(nm));
}

// ---------------- h = x @ W_embed  (N x 32 @ 32 x 64) ----------------
__global__ __launch_bounds__(256) void embed_mm(const float* __restrict__ x,
                                                const float* __restrict__ W,
                                                float* __restrict__ h) {
    __shared__ float Ws[IN_DIM * DD];
    int t = threadIdx.x;
    for (int i = t; i < IN_DIM * DD; i += 256) Ws[i] = W[i];
    __syncthreads();
    long n = (long)blockIdx.x * 256 + t;
    if (n >= NN) return;
    float acc[DD];
#pragma unroll
    for (int d = 0; d < DD; ++d) acc[d] = 0.f;
    const float4* xr = (const float4*)(x + n * IN_DIM);
#pragma unroll
    for (int k4 = 0; k4 < IN_DIM / 4; ++k4) {
        float4 xv = xr[k4];
        const float* xp = (const float*)&xv;
#pragma unroll
        for (int kk = 0; kk < 4; ++kk) {
            float v = xp[kk];
            int k = k4 * 4 + kk;
#pragma unroll
            for (int d = 0; d < DD; ++d) acc[d] += v * Ws[k * DD + d];
        }
    }
    float4* o = (float4*)(h + n * DD);
#pragma unroll
    for (int d4 = 0; d4 < DD / 4; ++d4)
        o[d4] = make_float4(acc[4 * d4], acc[4 * d4 + 1], acc[4 * d4 + 2], acc[4 * d4 + 3]);
}

// ---------------- out = h @ W  (N x 64 @ 64 x 64) ----------------
__global__ __launch_bounds__(256) void lin_mm(const float* __restrict__ h,
                                              const float* __restrict__ W,
                                              float* __restrict__ out) {
    __shared__ float Ws[DD * DD];
    int t = threadIdx.x;
    for (int i = t; i < DD * DD; i += 256) Ws[i] = W[i];
    __syncthreads();
    long n = (long)blockIdx.x * 256 + t;
    if (n >= NN) return;
    float acc[DD];
#pragma unroll
    for (int d = 0; d < DD; ++d) acc[d] = 0.f;
    const float4* hr = (const float4*)(h + n * DD);
#pragma unroll
    for (int k4 = 0; k4 < DD / 4; ++k4) {
        float4 hv = hr[k4];
        const float* hp = (const float*)&hv;
#pragma unroll
        for (int kk = 0; kk < 4; ++kk) {
            float v = hp[kk];
            int k = k4 * 4 + kk;
#pragma unroll
            for (int d = 0; d < DD; ++d) acc[d] += v * Ws[k * DD + d];
        }
    }
    float4* o = (float4*)(out + n * DD);
#pragma unroll
    for (int d4 = 0; d4 < DD / 4; ++d4)
        o[d4] = make_float4(acc[4 * d4], acc[4 * d4 + 1], acc[4 * d4 + 2], acc[4 * d4 + 3]);
}

// ---------------- fused: agg = self + bias + gather-sum; BN partial stats ----------------
__global__ __launch_bounds__(256) void gcn_agg(const float* __restrict__ hw,
                                               const float* __restrict__ dis,
                                               const int* __restrict__ cnt,
                                               const int* __restrict__ start,
                                               const int2* __restrict__ epack,
                                               const float* __restrict__ bias,
                                               float* __restrict__ agg,
                                               float* __restrict__ part) {
    int t = threadIdx.x;
    int g = t >> 6, d = t & 63;
    float s1 = 0.f, s2 = 0.f;
    float bd = bias[d];
    for (long n = (long)blockIdx.x * 4 + g; n < NN; n += (long)gridDim.x * 4) {
        float sn = dis[n];
        float acc = hw[n * DD + d] * (sn * sn) + bd;
        int rs = start[n];
        int ce = cnt[n];
        for (int i = 0; i < ce; ++i) {
            int2 ep = epack[rs + i];
            acc += hw[(long)ep.x * DD + d] * __int_as_float(ep.y);
        }
        agg[n * DD + d] = acc;
        s1 += acc;
        s2 += acc * acc;
    }
    __shared__ float ls[256], ls2[256];
    ls[t] = s1;
    ls2[t] = s2;
    __syncthreads();
    if (t < 64) {
        float a = ls[t] + ls[t + 64] + ls[t + 128] + ls[t + 192];
        float b = ls2[t] + ls2[t + 64] + ls2[t + 128] + ls2[t + 192];
        part[(long)blockIdx.x * 128 + t] = a;
        part[(long)blockIdx.x * 128 + 64 + t] = b;
    }
}

// ---------------- reduce per-block partials -> sums[128] (deterministic) ----------------
__global__ void bn_reduce(const float* __restrict__ part, float* __restrict__ sums) {
    int c = threadIdx.x;  // 0..127
    float a0 = 0.f, a1 = 0.f, a2 = 0.f, a3 = 0.f;
    for (int b = 0; b < AGG_BLOCKS; b += 4) {
        a0 += part[(long)b * 128 + c];
        a1 += part[(long)(b + 1) * 128 + c];
        a2 += part[(long)(b + 2) * 128 + c];
        a3 += part[(long)(b + 3) * 128 + c];
    }
    sums[c] = (a0 + a1) + (a2 + a3);
}

// ---------------- BN apply (+optional ReLU) ----------------
__global__ void bn_apply(const float* __restrict__ agg, const float* __restrict__ sums,
                         const float* __restrict__ g, const float* __restrict__ bt,
                         float* __restrict__ out, int relu) {
    long i = (long)blockIdx.x * blockDim.x + threadIdx.x;
    if (i >= (long)NN * DD) return;
    int d = (int)(i & 63);
    const float inv_n = 1.0f / (float)NN;
    float mu = sums[d] * inv_n;
    float var = sums[64 + d] * inv_n - mu * mu;
    float sc = g[d] * rsqrtf(var + BN_EPS);
    float v = (agg[i] - mu) * sc + bt[d];
    if (relu) v = fmaxf(v, 0.f);
    out[i] = v;
}

// ---------------- pool: batch is sorted -> run-length + flush ----------------
__global__ void zero_f32(float* __restrict__ p, long n) {
    long i = (long)blockIdx.x * blockDim.x + threadIdx.x;
    if (i < n) p[i] = 0.f;
}

__global__ __launch_bounds__(256) void pool_k(const float* __restrict__ h,
                                              const int* __restrict__ batch,
                                              float* __restrict__ pool) {
    const int ROWS = 256;
    int t = threadIdx.x;
    int d = t & 63;
    int rq = t >> 6;
    long base = (long)blockIdx.x * ROWS;
    float acc = 0.f;
    int cur = -1;
    for (int i = 0; i < ROWS / 4; ++i) {
        long r = base + rq + 4 * i;
        if (r >= NN) break;
        int b = batch[r];
        float v = h[r * DD + d];
        if (b != cur) {
            if (cur >= 0) atomicAdd(&pool[(long)cur * DD + d], acc);
            acc = 0.f;
            cur = b;
        }
        acc += v;
    }
    if (cur >= 0) atomicAdd(&pool[(long)cur * DD + d], acc);
}

extern "C" void kernel_launch(void* const* d_in, const int* in_sizes, int n_in,
                              void* d_out, int out_size, void* d_ws, size_t ws_size,
                              hipStream_t stream) {
    const float* x = (const float*)d_in[0];
    const int* ei = (const int*)d_in[1];
    const int* batch = (const int*)d_in[2];
    const float* W_embed = (const float*)d_in[3];
    const float* W1 = (const float*)d_in[4];
    const float* b1 = (const float*)d_in[5];
    const float* g1 = (const float*)d_in[6];
    const float* bt1 = (const float*)d_in[7];
    const float* W2 = (const float*)d_in[8];
    const float* b2 = (const float*)d_in[9];
    const float* g2 = (const float*)d_in[10];
    const float* bt2 = (const float*)d_in[11];

    const int* src = ei;
    const int* dst = ei + NE;

    float* out = (float*)d_out;         // h: N*DD floats
    float* pool = out + (long)NN * DD;  // h_pool: NG*DD floats

    const long ND = (long)NN * DD;

    // workspace layout
    char* w = (char*)d_ws;
    float* dis = (float*)w;               w += sizeof(float) * NN;
    int* cnt = (int*)w;                   w += sizeof(int) * NN;
    int* start = (int*)w;                 w += sizeof(int) * NN;
    int* cur = (int*)w;                   w += sizeof(int) * NN;
    int* cursor = (int*)w;                w += sizeof(int) * 4;     // keep alignment
    float* sums = (float*)w;              w += sizeof(float) * 128;
    float* part = (float*)w;              w += sizeof(float) * (long)AGG_BLOCKS * 128;
    int2* epack = (int2*)w;               w += sizeof(int2) * NE;
    float* A = (float*)w;                 w += sizeof(float) * ND;
    float* B = (float*)w;                 /* += sizeof(float)*ND */

    dim3 blk(256);
    const int nbN = (NN + 255) / 256;
    const int nbE = (NE + 255) / 256;
    const int nbND = (int)((ND + 255) / 256);

    // ---- CSR build ----
    zero_i32<<<dim3(nbN), blk, 0, stream>>>(cnt, NN);
    zero_i32<<<dim3(nbN), blk, 0, stream>>>(cur, NN);
    zero_i32<<<dim3(1), blk, 0, stream>>>(cursor, 1);
    zero_f32<<<dim3((NG * DD + 255) / 256), blk, 0, stream>>>(pool, (long)NG * DD);
    deg_count<<<dim3(nbE), blk, 0, stream>>>(dst, cnt);
    dis_k<<<dim3(nbN), blk, 0, stream>>>(cnt, dis);
    alloc_k<<<dim3(nbN), blk, 0, stream>>>(cnt, start, cursor);
    fill_edges<<<dim3(nbE), blk, 0, stream>>>(src, dst, dis, start, cur, epack);

    // ---- embed ----
    embed_mm<<<dim3(nbN), blk, 0, stream>>>(x, W_embed, A);

    // ---- layer 1: A -> A (relu) ----
    lin_mm<<<dim3(nbN), blk, 0, stream>>>(A, W1, B);
    gcn_agg<<<dim3(AGG_BLOCKS), blk, 0, stream>>>(B, dis, cnt, start, epack, b1, A, part);
    bn_reduce<<<dim3(1), dim3(128), 0, stream>>>(part, sums);
    bn_apply<<<dim3(nbND), blk, 0, stream>>>(A, sums, g1, bt1, A, 1);

    // ---- layer 2: A -> out ----
    lin_mm<<<dim3(nbN), blk, 0, stream>>>(A, W2, B);
    gcn_agg<<<dim3(AGG_BLOCKS), blk, 0, stream>>>(B, dis, cnt, start, epack, b2, A, part);
    bn_reduce<<<dim3(1), dim3(128), 0, stream>>>(part, sums);
    bn_apply<<<dim3(nbND), blk, 0, stream>>>(A, sums, g2, bt2, out, 0);

    // ---- pool ----
    pool_k<<<dim3(nbN), blk, 0, stream>>>(out, batch, pool);
}

// Round 3
// 637.842 us; speedup vs baseline: 1.5015x; 1.0537x over previous
//
#include <hip/hip_runtime.h>

#define NN 100000
#define NE 1600000
#define IN_DIM 32
#define DD 64
#define NG 128
#define BN_EPS 1e-5f
#define AGG_BLOCKS 2048

typedef unsigned short ushort_t;
typedef unsigned int uint_t;

__device__ __forceinline__ float bf2f(ushort_t u) {
    return __uint_as_float(((uint_t)u) << 16);
}
__device__ __forceinline__ ushort_t f2bf(float f) {
    uint_t u = __float_as_uint(f);
    u = (u + 0x7FFFu + ((u >> 16) & 1u)) >> 16;  // RNE
    return (ushort_t)u;
}

// ---------------- init: zero cnt[N], cur[N], cursor[4] (contiguous) + pool ----------------
__global__ void init_k(int* __restrict__ ints, long n_ints, float* __restrict__ pool) {
    long i = (long)blockIdx.x * blockDim.x + threadIdx.x;
    if (i < n_ints) ints[i] = 0;
    if (i < (long)NG * DD) pool[i] = 0.f;
}

__global__ void deg_count(const int* __restrict__ dst, int* __restrict__ cnt) {
    int e = blockIdx.x * blockDim.x + threadIdx.x;
    if (e < NE) atomicAdd(&cnt[dst[e]], 1);
}

// start[n] = block-local exclusive scan + atomic base; dis[n] = rsqrt(deg+1)
__global__ __launch_bounds__(256) void alloc_k(const int* __restrict__ cnt,
                                               int* __restrict__ start,
                                               int* __restrict__ cursor,
                                               float* __restrict__ dis) {
    __shared__ int ls[256];
    __shared__ int base_s;
    int t = threadIdx.x;
    long n = (long)blockIdx.x * 256 + t;
    int v = (n < NN) ? cnt[n] : 0;
    ls[t] = v;
    __syncthreads();
    for (int off = 1; off < 256; off <<= 1) {
        int y = (t >= off) ? ls[t - off] : 0;
        __syncthreads();
        ls[t] += y;
        __syncthreads();
    }
    if (t == 0) base_s = atomicAdd(cursor, ls[255]);
    __syncthreads();
    if (n < NN) {
        start[n] = base_s + ls[t] - v;
        dis[n] = rsqrtf((float)v + 1.0f);
    }
}

// epack[slot] = {src, enorm}
__global__ void fill_edges(const int* __restrict__ src, const int* __restrict__ dstp,
                           const float* __restrict__ dis, const int* __restrict__ start,
                           int* __restrict__ cur, int2* __restrict__ epack) {
    int e = blockIdx.x * blockDim.x + threadIdx.x;
    if (e >= NE) return;
    int s = src[e], t = dstp[e];
    int p = atomicAdd(&cur[t], 1);
    float nm = dis[s] * dis[t];
    epack[start[t] + p] = make_int2(s, __float_as_int(nm));
}

// ---------------- W_eff = W_embed @ W1  (32x64 @ 64x64) ----------------
__global__ __launch_bounds__(256) void weff_k(const float* __restrict__ We,
                                              const float* __restrict__ W1,
                                              float* __restrict__ Weff) {
    __shared__ float W1s[DD * DD];
    int t = threadIdx.x;
    for (int i = t; i < DD * DD; i += 256) W1s[i] = W1[i];
    __syncthreads();
    for (int idx = t; idx < IN_DIM * DD; idx += 256) {
        int i = idx >> 6, j = idx & 63;
        float s = 0.f;
#pragma unroll
        for (int k = 0; k < DD; ++k) s += We[i * DD + k] * W1s[k * DD + j];
        Weff[idx] = s;
    }
}

// ---------------- hw1 = x @ W_eff  (N x 32 @ 32 x 64) -> bf16 ----------------
__global__ __launch_bounds__(256) void mm1_k(const float* __restrict__ x,
                                             const float* __restrict__ Weff,
                                             ushort_t* __restrict__ hwb) {
    __shared__ float Ws[IN_DIM * DD];
    int t = threadIdx.x;
    for (int i = t; i < IN_DIM * DD; i += 256) Ws[i] = Weff[i];
    __syncthreads();
    long n = (long)blockIdx.x * 256 + t;
    if (n >= NN) return;
    float acc[DD];
#pragma unroll
    for (int d = 0; d < DD; ++d) acc[d] = 0.f;
    const float4* xr = (const float4*)(x + n * IN_DIM);
#pragma unroll
    for (int k4 = 0; k4 < IN_DIM / 4; ++k4) {
        float4 xv = xr[k4];
        const float* xp = (const float*)&xv;
#pragma unroll
        for (int kk = 0; kk < 4; ++kk) {
            float v = xp[kk];
            int k = k4 * 4 + kk;
#pragma unroll
            for (int d = 0; d < DD; ++d) acc[d] += v * Ws[k * DD + d];
        }
    }
    uint_t* o = (uint_t*)(hwb + n * DD);
#pragma unroll
    for (int d2 = 0; d2 < DD / 2; ++d2)
        o[d2] = (uint_t)f2bf(acc[2 * d2]) | ((uint_t)f2bf(acc[2 * d2 + 1]) << 16);
}

// ---------------- hw2 = BN1(agg1)+ReLU @ W2 -> bf16 ----------------
__global__ __launch_bounds__(256) void mm2_bn_k(const float* __restrict__ agg,
                                                const float* __restrict__ sums,
                                                const float* __restrict__ g,
                                                const float* __restrict__ bt,
                                                const float* __restrict__ W,
                                                ushort_t* __restrict__ hwb) {
    __shared__ float Ws[DD * DD];
    __shared__ float mu_s[DD], sc_s[DD], bt_s[DD];
    int t = threadIdx.x;
    for (int i = t; i < DD * DD; i += 256) Ws[i] = W[i];
    if (t < DD) {
        const float inv_n = 1.0f / (float)NN;
        float mu = sums[t] * inv_n;
        float var = sums[64 + t] * inv_n - mu * mu;
        mu_s[t] = mu;
        sc_s[t] = g[t] * rsqrtf(var + BN_EPS);
        bt_s[t] = bt[t];
    }
    __syncthreads();
    long n = (long)blockIdx.x * 256 + t;
    if (n >= NN) return;
    float acc[DD];
#pragma unroll
    for (int d = 0; d < DD; ++d) acc[d] = 0.f;
    const float4* ar = (const float4*)(agg + n * DD);
#pragma unroll
    for (int k4 = 0; k4 < DD / 4; ++k4) {
        float4 av = ar[k4];
        const float* ap = (const float*)&av;
#pragma unroll
        for (int kk = 0; kk < 4; ++kk) {
            int k = k4 * 4 + kk;
            float hv = fmaxf((ap[kk] - mu_s[k]) * sc_s[k] + bt_s[k], 0.f);
#pragma unroll
            for (int d = 0; d < DD; ++d) acc[d] += hv * Ws[k * DD + d];
        }
    }
    uint_t* o = (uint_t*)(hwb + n * DD);
#pragma unroll
    for (int d2 = 0; d2 < DD / 2; ++d2)
        o[d2] = (uint_t)f2bf(acc[2 * d2]) | ((uint_t)f2bf(acc[2 * d2 + 1]) << 16);
}

// ---------------- fused gather-aggregate (bf16 rows, unroll-4) + BN partials ----------------
__global__ __launch_bounds__(256) void gcn_agg(const ushort_t* __restrict__ hwb,
                                               const float* __restrict__ dis,
                                               const int* __restrict__ cnt,
                                               const int* __restrict__ start,
                                               const int2* __restrict__ epack,
                                               const float* __restrict__ bias,
                                               float* __restrict__ agg,
                                               float* __restrict__ part) {
    int t = threadIdx.x;
    int g = t >> 6, d = t & 63;
    float s1 = 0.f, s2 = 0.f;
    float bd = bias[d];
    for (long n = (long)blockIdx.x * 4 + g; n < NN; n += (long)gridDim.x * 4) {
        float sn = dis[n];
        float acc = bf2f(hwb[n * DD + d]) * (sn * sn) + bd;
        int rs = start[n];
        int ce = cnt[n];
        int i = 0;
        for (; i + 4 <= ce; i += 4) {
            int2 e0 = epack[rs + i + 0];
            int2 e1 = epack[rs + i + 1];
            int2 e2 = epack[rs + i + 2];
            int2 e3 = epack[rs + i + 3];
            float v0 = bf2f(hwb[(long)e0.x * DD + d]);
            float v1 = bf2f(hwb[(long)e1.x * DD + d]);
            float v2 = bf2f(hwb[(long)e2.x * DD + d]);
            float v3 = bf2f(hwb[(long)e3.x * DD + d]);
            acc += v0 * __int_as_float(e0.y);
            acc += v1 * __int_as_float(e1.y);
            acc += v2 * __int_as_float(e2.y);
            acc += v3 * __int_as_float(e3.y);
        }
        for (; i < ce; ++i) {
            int2 e = epack[rs + i];
            acc += bf2f(hwb[(long)e.x * DD + d]) * __int_as_float(e.y);
        }
        agg[n * DD + d] = acc;
        s1 += acc;
        s2 += acc * acc;
    }
    __shared__ float ls[256], ls2[256];
    ls[t] = s1;
    ls2[t] = s2;
    __syncthreads();
    if (t < 64) {
        float a = ls[t] + ls[t + 64] + ls[t + 128] + ls[t + 192];
        float b = ls2[t] + ls2[t + 64] + ls2[t + 128] + ls2[t + 192];
        part[(long)blockIdx.x * 128 + t] = a;
        part[(long)blockIdx.x * 128 + 64 + t] = b;
    }
}

// ---------------- deterministic partial reduce -> sums[128] ----------------
__global__ __launch_bounds__(512) void bn_reduce(const float* __restrict__ part,
                                                 float* __restrict__ sums) {
    __shared__ float ls[512];
    int t = threadIdx.x;
    int c = t & 127, q = t >> 7;  // 4 stripes per channel
    float a = 0.f;
    for (int b = q; b < AGG_BLOCKS; b += 4) a += part[(long)b * 128 + c];
    ls[t] = a;
    __syncthreads();
    if (t < 128) sums[t] = ls[t] + ls[t + 128] + ls[t + 256] + ls[t + 384];
}

// ---------------- BN2 apply + global_add_pool (batch sorted, run-length) ----------------
__global__ __launch_bounds__(256) void bn_pool(const float* __restrict__ agg,
                                               const float* __restrict__ sums,
                                               const float* __restrict__ g,
                                               const float* __restrict__ bt,
                                               const int* __restrict__ batch,
                                               float* __restrict__ out,
                                               float* __restrict__ pool) {
    int t = threadIdx.x;
    int d = t & 63, rq = t >> 6;
    const float inv_n = 1.0f / (float)NN;
    float mu = sums[d] * inv_n;
    float var = sums[64 + d] * inv_n - mu * mu;
    float sc = g[d] * rsqrtf(var + BN_EPS);
    float bd = bt[d];
    long base = (long)blockIdx.x * 256;
    float acc = 0.f;
    int cur = -1;
    for (int i = 0; i < 64; ++i) {
        long r = base + rq + 4 * i;
        if (r >= NN) break;
        int b = batch[r];
        float v = (agg[r * DD + d] - mu) * sc + bd;
        out[r * DD + d] = v;
        if (b != cur) {
            if (cur >= 0) atomicAdd(&pool[(long)cur * DD + d], acc);
            acc = 0.f;
            cur = b;
        }
        acc += v;
    }
    if (cur >= 0) atomicAdd(&pool[(long)cur * DD + d], acc);
}

extern "C" void kernel_launch(void* const* d_in, const int* in_sizes, int n_in,
                              void* d_out, int out_size, void* d_ws, size_t ws_size,
                              hipStream_t stream) {
    const float* x = (const float*)d_in[0];
    const int* ei = (const int*)d_in[1];
    const int* batch = (const int*)d_in[2];
    const float* W_embed = (const float*)d_in[3];
    const float* W1 = (const float*)d_in[4];
    const float* b1 = (const float*)d_in[5];
    const float* g1 = (const float*)d_in[6];
    const float* bt1 = (const float*)d_in[7];
    const float* W2 = (const float*)d_in[8];
    const float* b2 = (const float*)d_in[9];
    const float* g2 = (const float*)d_in[10];
    const float* bt2 = (const float*)d_in[11];

    const int* src = ei;
    const int* dst = ei + NE;

    float* out = (float*)d_out;         // h: N*DD
    float* pool = out + (long)NN * DD;  // h_pool: NG*DD

    const long ND = (long)NN * DD;

    // workspace layout (cnt,cur,cursor contiguous for single zero pass)
    char* w = (char*)d_ws;
    int* cnt = (int*)w;          w += sizeof(int) * NN;
    int* cur = (int*)w;          w += sizeof(int) * NN;
    int* cursor = (int*)w;       w += sizeof(int) * 4;
    int* start = (int*)w;        w += sizeof(int) * NN;
    float* dis = (float*)w;      w += sizeof(float) * NN;
    float* sums = (float*)w;     w += sizeof(float) * 128;
    float* Weff = (float*)w;     w += sizeof(float) * IN_DIM * DD;
    float* part = (float*)w;     w += sizeof(float) * (long)AGG_BLOCKS * 128;
    int2* epack = (int2*)w;      w += sizeof(int2) * NE;
    ushort_t* hwb = (ushort_t*)w; w += sizeof(ushort_t) * ND;
    float* aggbuf = (float*)w;   /* += sizeof(float) * ND */

    dim3 blk(256);
    const int nbN = (NN + 255) / 256;
    const int nbE = (NE + 255) / 256;
    const long n_ints = 2L * NN + 4;

    // ---- CSR build + norms ----
    init_k<<<dim3((int)((n_ints + 255) / 256)), blk, 0, stream>>>(cnt, n_ints, pool);
    deg_count<<<dim3(nbE), blk, 0, stream>>>(dst, cnt);
    alloc_k<<<dim3(nbN), blk, 0, stream>>>(cnt, start, cursor, dis);
    fill_edges<<<dim3(nbE), blk, 0, stream>>>(src, dst, dis, start, cur, epack);

    // ---- fold W_embed@W1; hw1 = x @ W_eff (bf16) ----
    weff_k<<<dim3(1), blk, 0, stream>>>(W_embed, W1, Weff);
    mm1_k<<<dim3(nbN), blk, 0, stream>>>(x, Weff, hwb);

    // ---- layer 1 ----
    gcn_agg<<<dim3(AGG_BLOCKS), blk, 0, stream>>>(hwb, dis, cnt, start, epack, b1, aggbuf, part);
    bn_reduce<<<dim3(1), dim3(512), 0, stream>>>(part, sums);

    // ---- BN1+ReLU fused into layer-2 matmul ----
    mm2_bn_k<<<dim3(nbN), blk, 0, stream>>>(aggbuf, sums, g1, bt1, W2, hwb);

    // ---- layer 2 ----
    gcn_agg<<<dim3(AGG_BLOCKS), blk, 0, stream>>>(hwb, dis, cnt, start, epack, b2, aggbuf, part);
    bn_reduce<<<dim3(1), dim3(512), 0, stream>>>(part, sums);

    // ---- BN2 + write h + pool ----
    bn_pool<<<dim3(nbN), blk, 0, stream>>>(aggbuf, sums, g2, bt2, batch, out, pool);
}

// Round 4
// 501.511 us; speedup vs baseline: 1.9097x; 1.2718x over previous
//
#include <hip/hip_runtime.h>

#define NN 100000
#define NE 1600000
#define IN_DIM 32
#define DD 64
#define NG 128
#define BN_EPS 1e-5f
#define AGG_BLOCKS 1024

typedef unsigned short ushort_t;
typedef unsigned int uint_t;

__device__ __forceinline__ float bf2f(ushort_t u) {
    return __uint_as_float(((uint_t)u) << 16);
}
__device__ __forceinline__ ushort_t f2bf(float f) {
    uint_t u = __float_as_uint(f);
    u = (u + 0x7FFFu + ((u >> 16) & 1u)) >> 16;  // RNE
    return (ushort_t)u;
}
__device__ __forceinline__ uint_t pack2(float a, float b) {
    return (uint_t)f2bf(a) | ((uint_t)f2bf(b) << 16);
}

// ---------------- init: zero cnt/cur/cursor, pool, sums1+sums2 ----------------
__global__ void init_k(int* __restrict__ ints, long n_ints, float* __restrict__ pool,
                       float* __restrict__ sums) {
    long i = (long)blockIdx.x * blockDim.x + threadIdx.x;
    if (i < n_ints) ints[i] = 0;
    if (i < (long)NG * DD) pool[i] = 0.f;
    if (i < 256) sums[i] = 0.f;
}

__global__ void deg_count(const int* __restrict__ dst, int* __restrict__ cnt) {
    int e = blockIdx.x * blockDim.x + threadIdx.x;
    if (e < NE) atomicAdd(&cnt[dst[e]], 1);
}

// start[n] = block-local exclusive scan + atomic base; dis[n] = rsqrt(deg+1)
__global__ __launch_bounds__(256) void alloc_k(const int* __restrict__ cnt,
                                               int* __restrict__ start,
                                               int* __restrict__ cursor,
                                               float* __restrict__ dis) {
    __shared__ int ls[256];
    __shared__ int base_s;
    int t = threadIdx.x;
    long n = (long)blockIdx.x * 256 + t;
    int v = (n < NN) ? cnt[n] : 0;
    ls[t] = v;
    __syncthreads();
    for (int off = 1; off < 256; off <<= 1) {
        int y = (t >= off) ? ls[t - off] : 0;
        __syncthreads();
        ls[t] += y;
        __syncthreads();
    }
    if (t == 0) base_s = atomicAdd(cursor, ls[255]);
    __syncthreads();
    if (n < NN) {
        start[n] = base_s + ls[t] - v;
        dis[n] = rsqrtf((float)v + 1.0f);
    }
}

// epack[slot] = {src, enorm}
__global__ void fill_edges(const int* __restrict__ src, const int* __restrict__ dstp,
                           const float* __restrict__ dis, const int* __restrict__ start,
                           int* __restrict__ cur, int2* __restrict__ epack) {
    int e = blockIdx.x * blockDim.x + threadIdx.x;
    if (e >= NE) return;
    int s = src[e], t = dstp[e];
    int p = atomicAdd(&cur[t], 1);
    float nm = dis[s] * dis[t];
    epack[start[t] + p] = make_int2(s, __float_as_int(nm));
}

// ---------------- W_eff = W_embed @ W1  (32x64 @ 64x64) ----------------
__global__ __launch_bounds__(256) void weff_k(const float* __restrict__ We,
                                              const float* __restrict__ W1,
                                              float* __restrict__ Weff) {
    __shared__ float W1s[DD * DD];
    int t = threadIdx.x;
    for (int i = t; i < DD * DD; i += 256) W1s[i] = W1[i];
    __syncthreads();
    for (int idx = t; idx < IN_DIM * DD; idx += 256) {
        int i = idx >> 6, j = idx & 63;
        float s = 0.f;
#pragma unroll
        for (int k = 0; k < DD; ++k) s += We[i * DD + k] * W1s[k * DD + j];
        Weff[idx] = s;
    }
}

// ---------------- hw1 = x @ W_eff  (N x 32 @ 32 x 64) -> bf16 ----------------
__global__ __launch_bounds__(256) void mm1_k(const float* __restrict__ x,
                                             const float* __restrict__ Weff,
                                             ushort_t* __restrict__ hwb) {
    __shared__ float Ws[IN_DIM * DD];
    int t = threadIdx.x;
    for (int i = t; i < IN_DIM * DD; i += 256) Ws[i] = Weff[i];
    __syncthreads();
    long n = (long)blockIdx.x * 256 + t;
    if (n >= NN) return;
    float acc[DD];
#pragma unroll
    for (int d = 0; d < DD; ++d) acc[d] = 0.f;
    const float4* xr = (const float4*)(x + n * IN_DIM);
#pragma unroll
    for (int k4 = 0; k4 < IN_DIM / 4; ++k4) {
        float4 xv = xr[k4];
        const float* xp = (const float*)&xv;
#pragma unroll
        for (int kk = 0; kk < 4; ++kk) {
            float v = xp[kk];
            int k = k4 * 4 + kk;
#pragma unroll
            for (int d = 0; d < DD; ++d) acc[d] += v * Ws[k * DD + d];
        }
    }
    uint4* o = (uint4*)(hwb + n * DD);
#pragma unroll
    for (int d8 = 0; d8 < DD / 8; ++d8) {
        uint4 pk;
        pk.x = pack2(acc[8 * d8 + 0], acc[8 * d8 + 1]);
        pk.y = pack2(acc[8 * d8 + 2], acc[8 * d8 + 3]);
        pk.z = pack2(acc[8 * d8 + 4], acc[8 * d8 + 5]);
        pk.w = pack2(acc[8 * d8 + 6], acc[8 * d8 + 7]);
        o[d8] = pk;
    }
}

// ---------------- hw2 = BN1(agg1)+ReLU @ W2 -> bf16 ----------------
__global__ __launch_bounds__(256) void mm2_bn_k(const float* __restrict__ agg,
                                                const float* __restrict__ sums,
                                                const float* __restrict__ g,
                                                const float* __restrict__ bt,
                                                const float* __restrict__ W,
                                                ushort_t* __restrict__ hwb) {
    __shared__ float Ws[DD * DD];
    __shared__ float mu_s[DD], sc_s[DD], bt_s[DD];
    int t = threadIdx.x;
    for (int i = t; i < DD * DD; i += 256) Ws[i] = W[i];
    if (t < DD) {
        const float inv_n = 1.0f / (float)NN;
        float mu = sums[t] * inv_n;
        float var = sums[64 + t] * inv_n - mu * mu;
        mu_s[t] = mu;
        sc_s[t] = g[t] * rsqrtf(var + BN_EPS);
        bt_s[t] = bt[t];
    }
    __syncthreads();
    long n = (long)blockIdx.x * 256 + t;
    if (n >= NN) return;
    float acc[DD];
#pragma unroll
    for (int d = 0; d < DD; ++d) acc[d] = 0.f;
    const float4* ar = (const float4*)(agg + n * DD);
#pragma unroll
    for (int k4 = 0; k4 < DD / 4; ++k4) {
        float4 av = ar[k4];
        const float* ap = (const float*)&av;
#pragma unroll
        for (int kk = 0; kk < 4; ++kk) {
            int k = k4 * 4 + kk;
            float hv = fmaxf((ap[kk] - mu_s[k]) * sc_s[k] + bt_s[k], 0.f);
#pragma unroll
            for (int d = 0; d < DD; ++d) acc[d] += hv * Ws[k * DD + d];
        }
    }
    uint4* o = (uint4*)(hwb + n * DD);
#pragma unroll
    for (int d8 = 0; d8 < DD / 8; ++d8) {
        uint4 pk;
        pk.x = pack2(acc[8 * d8 + 0], acc[8 * d8 + 1]);
        pk.y = pack2(acc[8 * d8 + 2], acc[8 * d8 + 3]);
        pk.z = pack2(acc[8 * d8 + 4], acc[8 * d8 + 5]);
        pk.w = pack2(acc[8 * d8 + 6], acc[8 * d8 + 7]);
        o[d8] = pk;
    }
}

// ------- fused gather-aggregate (bf16 rows, unroll-4) + BN stats via atomics -------
__global__ __launch_bounds__(256) void gcn_agg(const ushort_t* __restrict__ hwb,
                                               const float* __restrict__ dis,
                                               const int* __restrict__ cnt,
                                               const int* __restrict__ start,
                                               const int2* __restrict__ epack,
                                               const float* __restrict__ bias,
                                               float* __restrict__ agg,
                                               float* __restrict__ sums) {
    int t = threadIdx.x;
    int g = t >> 6, d = t & 63;
    float s1 = 0.f, s2 = 0.f;
    float bd = bias[d];
    for (long n = (long)blockIdx.x * 4 + g; n < NN; n += (long)gridDim.x * 4) {
        float sn = dis[n];
        float acc = bf2f(hwb[n * DD + d]) * (sn * sn) + bd;
        int rs = start[n];
        int ce = cnt[n];
        int i = 0;
        for (; i + 4 <= ce; i += 4) {
            int2 e0 = epack[rs + i + 0];
            int2 e1 = epack[rs + i + 1];
            int2 e2 = epack[rs + i + 2];
            int2 e3 = epack[rs + i + 3];
            float v0 = bf2f(hwb[(long)e0.x * DD + d]);
            float v1 = bf2f(hwb[(long)e1.x * DD + d]);
            float v2 = bf2f(hwb[(long)e2.x * DD + d]);
            float v3 = bf2f(hwb[(long)e3.x * DD + d]);
            acc += v0 * __int_as_float(e0.y);
            acc += v1 * __int_as_float(e1.y);
            acc += v2 * __int_as_float(e2.y);
            acc += v3 * __int_as_float(e3.y);
        }
        for (; i < ce; ++i) {
            int2 e = epack[rs + i];
            acc += bf2f(hwb[(long)e.x * DD + d]) * __int_as_float(e.y);
        }
        agg[n * DD + d] = acc;
        s1 += acc;
        s2 += acc * acc;
    }
    __shared__ float ls[256], ls2[256];
    ls[t] = s1;
    ls2[t] = s2;
    __syncthreads();
    if (t < 64) {
        float a = ls[t] + ls[t + 64] + ls[t + 128] + ls[t + 192];
        float b = ls2[t] + ls2[t + 64] + ls2[t + 128] + ls2[t + 192];
        atomicAdd(&sums[t], a);
        atomicAdd(&sums[64 + t], b);
    }
}

// ---------------- BN2 apply + global_add_pool (batch sorted, run-length) ----------------
__global__ __launch_bounds__(256) void bn_pool(const float* __restrict__ agg,
                                               const float* __restrict__ sums,
                                               const float* __restrict__ g,
                                               const float* __restrict__ bt,
                                               const int* __restrict__ batch,
                                               float* __restrict__ out,
                                               float* __restrict__ pool) {
    int t = threadIdx.x;
    int d = t & 63, rq = t >> 6;
    const float inv_n = 1.0f / (float)NN;
    float mu = sums[d] * inv_n;
    float var = sums[64 + d] * inv_n - mu * mu;
    float sc = g[d] * rsqrtf(var + BN_EPS);
    float bd = bt[d];
    long base = (long)blockIdx.x * 256;
    float acc = 0.f;
    int cur = -1;
    for (int i = 0; i < 64; ++i) {
        long r = base + rq + 4 * i;
        if (r >= NN) break;
        int b = batch[r];
        float v = (agg[r * DD + d] - mu) * sc + bd;
        out[r * DD + d] = v;
        if (b != cur) {
            if (cur >= 0) atomicAdd(&pool[(long)cur * DD + d], acc);
            acc = 0.f;
            cur = b;
        }
        acc += v;
    }
    if (cur >= 0) atomicAdd(&pool[(long)cur * DD + d], acc);
}

extern "C" void kernel_launch(void* const* d_in, const int* in_sizes, int n_in,
                              void* d_out, int out_size, void* d_ws, size_t ws_size,
                              hipStream_t stream) {
    const float* x = (const float*)d_in[0];
    const int* ei = (const int*)d_in[1];
    const int* batch = (const int*)d_in[2];
    const float* W_embed = (const float*)d_in[3];
    const float* W1 = (const float*)d_in[4];
    const float* b1 = (const float*)d_in[5];
    const float* g1 = (const float*)d_in[6];
    const float* bt1 = (const float*)d_in[7];
    const float* W2 = (const float*)d_in[8];
    const float* b2 = (const float*)d_in[9];
    const float* g2 = (const float*)d_in[10];
    const float* bt2 = (const float*)d_in[11];

    const int* src = ei;
    const int* dst = ei + NE;

    float* out = (float*)d_out;         // h: N*DD
    float* pool = out + (long)NN * DD;  // h_pool: NG*DD

    const long ND = (long)NN * DD;

    // workspace layout (cnt,cur,cursor contiguous for single zero pass)
    char* w = (char*)d_ws;
    int* cnt = (int*)w;          w += sizeof(int) * NN;
    int* cur = (int*)w;          w += sizeof(int) * NN;
    int* cursor = (int*)w;       w += sizeof(int) * 4;
    int* start = (int*)w;        w += sizeof(int) * NN;
    float* dis = (float*)w;      w += sizeof(float) * NN;
    float* sums1 = (float*)w;    w += sizeof(float) * 128;   // sums1+sums2 contiguous (256)
    float* sums2 = (float*)w;    w += sizeof(float) * 128;
    float* Weff = (float*)w;     w += sizeof(float) * IN_DIM * DD;
    int2* epack = (int2*)w;      w += sizeof(int2) * NE;
    ushort_t* hwb = (ushort_t*)w; w += sizeof(ushort_t) * ND;
    float* aggbuf = (float*)w;   /* += sizeof(float) * ND */

    dim3 blk(256);
    const int nbN = (NN + 255) / 256;
    const int nbE = (NE + 255) / 256;
    const long n_ints = 2L * NN + 4;

    // ---- CSR build + norms ----
    init_k<<<dim3((int)((n_ints + 255) / 256)), blk, 0, stream>>>(cnt, n_ints, pool, sums1);
    deg_count<<<dim3(nbE), blk, 0, stream>>>(dst, cnt);
    alloc_k<<<dim3(nbN), blk, 0, stream>>>(cnt, start, cursor, dis);
    fill_edges<<<dim3(nbE), blk, 0, stream>>>(src, dst, dis, start, cur, epack);

    // ---- fold W_embed@W1; hw1 = x @ W_eff (bf16) ----
    weff_k<<<dim3(1), blk, 0, stream>>>(W_embed, W1, Weff);
    mm1_k<<<dim3(nbN), blk, 0, stream>>>(x, Weff, hwb);

    // ---- layer 1 (BN stats accumulated atomically into sums1) ----
    gcn_agg<<<dim3(AGG_BLOCKS), blk, 0, stream>>>(hwb, dis, cnt, start, epack, b1, aggbuf, sums1);

    // ---- BN1+ReLU fused into layer-2 matmul ----
    mm2_bn_k<<<dim3(nbN), blk, 0, stream>>>(aggbuf, sums1, g1, bt1, W2, hwb);

    // ---- layer 2 (stats into sums2) ----
    gcn_agg<<<dim3(AGG_BLOCKS), blk, 0, stream>>>(hwb, dis, cnt, start, epack, b2, aggbuf, sums2);

    // ---- BN2 + write h + pool ----
    bn_pool<<<dim3(nbN), blk, 0, stream>>>(aggbuf, sums2, g2, bt2, batch, out, pool);
}

// Round 5
// 498.132 us; speedup vs baseline: 1.9226x; 1.0068x over previous
//
#include <hip/hip_runtime.h>

#define NN 100000
#define NE 1600000
#define IN_DIM 32
#define DD 64
#define NG 128
#define BN_EPS 1e-5f
#define AGG_BLOCKS 2048

typedef unsigned short ushort_t;
typedef unsigned int uint_t;

__device__ __forceinline__ float bf2f(ushort_t u) {
    return __uint_as_float(((uint_t)u) << 16);
}
__device__ __forceinline__ ushort_t f2bf(float f) {
    uint_t u = __float_as_uint(f);
    u = (u + 0x7FFFu + ((u >> 16) & 1u)) >> 16;  // RNE
    return (ushort_t)u;
}
__device__ __forceinline__ uint_t pack2(float a, float b) {
    return (uint_t)f2bf(a) | ((uint_t)f2bf(b) << 16);
}
__device__ __forceinline__ float bflo(uint_t u) { return __uint_as_float(u << 16); }
__device__ __forceinline__ float bfhi(uint_t u) { return __uint_as_float(u & 0xFFFF0000u); }

// ---------------- init: zero cnt/cur/cursor, pool, sums1+sums2 ----------------
__global__ void init_k(int* __restrict__ ints, long n_ints, float* __restrict__ pool,
                       float* __restrict__ sums) {
    long i = (long)blockIdx.x * blockDim.x + threadIdx.x;
    if (i < n_ints) ints[i] = 0;
    if (i < (long)NG * DD) pool[i] = 0.f;
    if (i < 256) sums[i] = 0.f;
}

__global__ void deg_count(const int* __restrict__ dst, int* __restrict__ cnt) {
    int e = blockIdx.x * blockDim.x + threadIdx.x;
    if (e < NE) atomicAdd(&cnt[dst[e]], 1);
}

// start[n] = block-local exclusive scan + atomic base; dis[n] = rsqrt(deg+1)
__global__ __launch_bounds__(256) void alloc_k(const int* __restrict__ cnt,
                                               int* __restrict__ start,
                                               int* __restrict__ cursor,
                                               float* __restrict__ dis) {
    __shared__ int ls[256];
    __shared__ int base_s;
    int t = threadIdx.x;
    long n = (long)blockIdx.x * 256 + t;
    int v = (n < NN) ? cnt[n] : 0;
    ls[t] = v;
    __syncthreads();
    for (int off = 1; off < 256; off <<= 1) {
        int y = (t >= off) ? ls[t - off] : 0;
        __syncthreads();
        ls[t] += y;
        __syncthreads();
    }
    if (t == 0) base_s = atomicAdd(cursor, ls[255]);
    __syncthreads();
    if (n < NN) {
        start[n] = base_s + ls[t] - v;
        dis[n] = rsqrtf((float)v + 1.0f);
    }
}

// epack[slot] = {src, enorm}
__global__ void fill_edges(const int* __restrict__ src, const int* __restrict__ dstp,
                           const float* __restrict__ dis, const int* __restrict__ start,
                           int* __restrict__ cur, int2* __restrict__ epack) {
    int e = blockIdx.x * blockDim.x + threadIdx.x;
    if (e >= NE) return;
    int s = src[e], t = dstp[e];
    int p = atomicAdd(&cur[t], 1);
    float nm = dis[s] * dis[t];
    epack[start[t] + p] = make_int2(s, __float_as_int(nm));
}

// ---------------- W_eff = W_embed @ W1  (32x64 @ 64x64) ----------------
__global__ __launch_bounds__(256) void weff_k(const float* __restrict__ We,
                                              const float* __restrict__ W1,
                                              float* __restrict__ Weff) {
    __shared__ float W1s[DD * DD];
    int t = threadIdx.x;
    for (int i = t; i < DD * DD; i += 256) W1s[i] = W1[i];
    __syncthreads();
    for (int idx = t; idx < IN_DIM * DD; idx += 256) {
        int i = idx >> 6, j = idx & 63;
        float s = 0.f;
#pragma unroll
        for (int k = 0; k < DD; ++k) s += We[i * DD + k] * W1s[k * DD + j];
        Weff[idx] = s;
    }
}

// ---------------- hw1 = x @ W_eff  (N x 32 @ 32 x 64) -> bf16 ----------------
__global__ __launch_bounds__(256) void mm1_k(const float* __restrict__ x,
                                             const float* __restrict__ Weff,
                                             ushort_t* __restrict__ hwb) {
    __shared__ float Ws[IN_DIM * DD];
    int t = threadIdx.x;
    for (int i = t; i < IN_DIM * DD; i += 256) Ws[i] = Weff[i];
    __syncthreads();
    long n = (long)blockIdx.x * 256 + t;
    if (n >= NN) return;
    float acc[DD];
#pragma unroll
    for (int d = 0; d < DD; ++d) acc[d] = 0.f;
    const float4* xr = (const float4*)(x + n * IN_DIM);
#pragma unroll
    for (int k4 = 0; k4 < IN_DIM / 4; ++k4) {
        float4 xv = xr[k4];
        const float* xp = (const float*)&xv;
#pragma unroll
        for (int kk = 0; kk < 4; ++kk) {
            float v = xp[kk];
            int k = k4 * 4 + kk;
#pragma unroll
            for (int d = 0; d < DD; ++d) acc[d] += v * Ws[k * DD + d];
        }
    }
    uint4* o = (uint4*)(hwb + n * DD);
#pragma unroll
    for (int d8 = 0; d8 < DD / 8; ++d8) {
        uint4 pk;
        pk.x = pack2(acc[8 * d8 + 0], acc[8 * d8 + 1]);
        pk.y = pack2(acc[8 * d8 + 2], acc[8 * d8 + 3]);
        pk.z = pack2(acc[8 * d8 + 4], acc[8 * d8 + 5]);
        pk.w = pack2(acc[8 * d8 + 6], acc[8 * d8 + 7]);
        o[d8] = pk;
    }
}

// ---------------- hw2 = BN1(agg1)+ReLU @ W2 -> bf16 ----------------
__global__ __launch_bounds__(256) void mm2_bn_k(const float* __restrict__ agg,
                                                const float* __restrict__ sums,
                                                const float* __restrict__ g,
                                                const float* __restrict__ bt,
                                                const float* __restrict__ W,
                                                ushort_t* __restrict__ hwb) {
    __shared__ float Ws[DD * DD];
    __shared__ float mu_s[DD], sc_s[DD], bt_s[DD];
    int t = threadIdx.x;
    for (int i = t; i < DD * DD; i += 256) Ws[i] = W[i];
    if (t < DD) {
        const float inv_n = 1.0f / (float)NN;
        float mu = sums[t] * inv_n;
        float var = sums[64 + t] * inv_n - mu * mu;
        mu_s[t] = mu;
        sc_s[t] = g[t] * rsqrtf(var + BN_EPS);
        bt_s[t] = bt[t];
    }
    __syncthreads();
    long n = (long)blockIdx.x * 256 + t;
    if (n >= NN) return;
    float acc[DD];
#pragma unroll
    for (int d = 0; d < DD; ++d) acc[d] = 0.f;
    const float4* ar = (const float4*)(agg + n * DD);
#pragma unroll
    for (int k4 = 0; k4 < DD / 4; ++k4) {
        float4 av = ar[k4];
        const float* ap = (const float*)&av;
#pragma unroll
        for (int kk = 0; kk < 4; ++kk) {
            int k = k4 * 4 + kk;
            float hv = fmaxf((ap[kk] - mu_s[k]) * sc_s[k] + bt_s[k], 0.f);
#pragma unroll
            for (int d = 0; d < DD; ++d) acc[d] += hv * Ws[k * DD + d];
        }
    }
    uint4* o = (uint4*)(hwb + n * DD);
#pragma unroll
    for (int d8 = 0; d8 < DD / 8; ++d8) {
        uint4 pk;
        pk.x = pack2(acc[8 * d8 + 0], acc[8 * d8 + 1]);
        pk.y = pack2(acc[8 * d8 + 2], acc[8 * d8 + 3]);
        pk.z = pack2(acc[8 * d8 + 4], acc[8 * d8 + 5]);
        pk.w = pack2(acc[8 * d8 + 6], acc[8 * d8 + 7]);
        o[d8] = pk;
    }
}

// ------- gather-aggregate: 8 lanes/row uint4, 16 edges in flight, shfl reduce -------
__global__ __launch_bounds__(256) void gcn_agg(const ushort_t* __restrict__ hwb,
                                               const float* __restrict__ dis,
                                               const int* __restrict__ cnt,
                                               const int* __restrict__ start,
                                               const int2* __restrict__ epack,
                                               const float* __restrict__ bias,
                                               float* __restrict__ agg,
                                               float* __restrict__ sums) {
    int t = threadIdx.x;
    int w = t >> 6;       // wave in block (0..3)
    int lane = t & 63;
    int j = lane >> 3;    // edge slot 0..7
    int c = lane & 7;     // channel group -> channels 8c..8c+7
    float selfmask = (j == 0) ? 1.f : 0.f;

    float bs[8];
#pragma unroll
    for (int k = 0; k < 8; ++k) bs[k] = bias[8 * c + k];

    float s1[8], s2[8];
#pragma unroll
    for (int k = 0; k < 8; ++k) { s1[k] = 0.f; s2[k] = 0.f; }

    for (long n = (long)blockIdx.x * 4 + w; n < NN; n += (long)gridDim.x * 4) {
        int rs = start[n];
        int ce = cnt[n];
        float sn = dis[n];
        float sq = sn * sn;

        // init: self-loop + bias, contributed once via j==0 slice
        const uint4* sp = (const uint4*)(hwb + (long)n * DD);
        uint4 sv = sp[c];
        float acc[8];
        acc[0] = selfmask * (bflo(sv.x) * sq + bs[0]);
        acc[1] = selfmask * (bfhi(sv.x) * sq + bs[1]);
        acc[2] = selfmask * (bflo(sv.y) * sq + bs[2]);
        acc[3] = selfmask * (bfhi(sv.y) * sq + bs[3]);
        acc[4] = selfmask * (bflo(sv.z) * sq + bs[4]);
        acc[5] = selfmask * (bfhi(sv.z) * sq + bs[5]);
        acc[6] = selfmask * (bflo(sv.w) * sq + bs[6]);
        acc[7] = selfmask * (bfhi(sv.w) * sq + bs[7]);

        for (int i = 0; i < ce; i += 16) {
            int i0 = i + j, i1 = i + 8 + j;
            int2 e0 = (i0 < ce) ? epack[rs + i0] : make_int2(0, 0);
            int2 e1 = (i1 < ce) ? epack[rs + i1] : make_int2(0, 0);
            const uint4* r0 = (const uint4*)(hwb + (long)e0.x * DD);
            const uint4* r1 = (const uint4*)(hwb + (long)e1.x * DD);
            uint4 q0 = r0[c];
            uint4 q1 = r1[c];
            float n0 = __int_as_float(e0.y);
            float n1 = __int_as_float(e1.y);
            acc[0] += bflo(q0.x) * n0; acc[1] += bfhi(q0.x) * n0;
            acc[2] += bflo(q0.y) * n0; acc[3] += bfhi(q0.y) * n0;
            acc[4] += bflo(q0.z) * n0; acc[5] += bfhi(q0.z) * n0;
            acc[6] += bflo(q0.w) * n0; acc[7] += bfhi(q0.w) * n0;
            acc[0] += bflo(q1.x) * n1; acc[1] += bfhi(q1.x) * n1;
            acc[2] += bflo(q1.y) * n1; acc[3] += bfhi(q1.y) * n1;
            acc[4] += bflo(q1.z) * n1; acc[5] += bfhi(q1.z) * n1;
            acc[6] += bflo(q1.w) * n1; acc[7] += bfhi(q1.w) * n1;
        }

        // reduce over edge slots j (lane bits 3..5)
#pragma unroll
        for (int m = 8; m < 64; m <<= 1) {
#pragma unroll
            for (int k = 0; k < 8; ++k) acc[k] += __shfl_xor(acc[k], m, 64);
        }

        if (j == 0) {  // lanes 0..7 write row + collect stats
            float4* op = (float4*)(agg + (long)n * DD);
            op[2 * c] = make_float4(acc[0], acc[1], acc[2], acc[3]);
            op[2 * c + 1] = make_float4(acc[4], acc[5], acc[6], acc[7]);
#pragma unroll
            for (int k = 0; k < 8; ++k) {
                s1[k] += acc[k];
                s2[k] += acc[k] * acc[k];
            }
        }
    }

    __shared__ float ls[4][128];
    if (j == 0) {
#pragma unroll
        for (int k = 0; k < 8; ++k) {
            ls[w][8 * c + k] = s1[k];
            ls[w][64 + 8 * c + k] = s2[k];
        }
    }
    __syncthreads();
    if (t < 128) {
        float a = ls[0][t] + ls[1][t] + ls[2][t] + ls[3][t];
        atomicAdd(&sums[t], a);
    }
}

// ---------------- BN2 apply + global_add_pool (batch sorted, run-length) ----------------
__global__ __launch_bounds__(256) void bn_pool(const float* __restrict__ agg,
                                               const float* __restrict__ sums,
                                               const float* __restrict__ g,
                                               const float* __restrict__ bt,
                                               const int* __restrict__ batch,
                                               float* __restrict__ out,
                                               float* __restrict__ pool) {
    int t = threadIdx.x;
    int d = t & 63, rq = t >> 6;
    const float inv_n = 1.0f / (float)NN;
    float mu = sums[d] * inv_n;
    float var = sums[64 + d] * inv_n - mu * mu;
    float sc = g[d] * rsqrtf(var + BN_EPS);
    float bd = bt[d];
    long base = (long)blockIdx.x * 256;
    float acc = 0.f;
    int cur = -1;
    for (int i = 0; i < 64; ++i) {
        long r = base + rq + 4 * i;
        if (r >= NN) break;
        int b = batch[r];
        float v = (agg[r * DD + d] - mu) * sc + bd;
        out[r * DD + d] = v;
        if (b != cur) {
            if (cur >= 0) atomicAdd(&pool[(long)cur * DD + d], acc);
            acc = 0.f;
            cur = b;
        }
        acc += v;
    }
    if (cur >= 0) atomicAdd(&pool[(long)cur * DD + d], acc);
}

extern "C" void kernel_launch(void* const* d_in, const int* in_sizes, int n_in,
                              void* d_out, int out_size, void* d_ws, size_t ws_size,
                              hipStream_t stream) {
    const float* x = (const float*)d_in[0];
    const int* ei = (const int*)d_in[1];
    const int* batch = (const int*)d_in[2];
    const float* W_embed = (const float*)d_in[3];
    const float* W1 = (const float*)d_in[4];
    const float* b1 = (const float*)d_in[5];
    const float* g1 = (const float*)d_in[6];
    const float* bt1 = (const float*)d_in[7];
    const float* W2 = (const float*)d_in[8];
    const float* b2 = (const float*)d_in[9];
    const float* g2 = (const float*)d_in[10];
    const float* bt2 = (const float*)d_in[11];

    const int* src = ei;
    const int* dst = ei + NE;

    float* out = (float*)d_out;         // h: N*DD
    float* pool = out + (long)NN * DD;  // h_pool: NG*DD

    const long ND = (long)NN * DD;

    // workspace layout (cnt,cur,cursor contiguous for single zero pass)
    char* w = (char*)d_ws;
    int* cnt = (int*)w;          w += sizeof(int) * NN;
    int* cur = (int*)w;          w += sizeof(int) * NN;
    int* cursor = (int*)w;       w += sizeof(int) * 4;
    int* start = (int*)w;        w += sizeof(int) * NN;
    float* dis = (float*)w;      w += sizeof(float) * NN;
    float* sums1 = (float*)w;    w += sizeof(float) * 128;   // sums1+sums2 contiguous (256)
    float* sums2 = (float*)w;    w += sizeof(float) * 128;
    float* Weff = (float*)w;     w += sizeof(float) * IN_DIM * DD;
    int2* epack = (int2*)w;      w += sizeof(int2) * NE;
    ushort_t* hwb = (ushort_t*)w; w += sizeof(ushort_t) * ND;
    float* aggbuf = (float*)w;   /* += sizeof(float) * ND */

    dim3 blk(256);
    const int nbN = (NN + 255) / 256;
    const int nbE = (NE + 255) / 256;
    const long n_ints = 2L * NN + 4;

    // ---- CSR build + norms ----
    init_k<<<dim3((int)((n_ints + 255) / 256)), blk, 0, stream>>>(cnt, n_ints, pool, sums1);
    deg_count<<<dim3(nbE), blk, 0, stream>>>(dst, cnt);
    alloc_k<<<dim3(nbN), blk, 0, stream>>>(cnt, start, cursor, dis);
    fill_edges<<<dim3(nbE), blk, 0, stream>>>(src, dst, dis, start, cur, epack);

    // ---- fold W_embed@W1; hw1 = x @ W_eff (bf16) ----
    weff_k<<<dim3(1), blk, 0, stream>>>(W_embed, W1, Weff);
    mm1_k<<<dim3(nbN), blk, 0, stream>>>(x, Weff, hwb);

    // ---- layer 1 (BN stats accumulated atomically into sums1) ----
    gcn_agg<<<dim3(AGG_BLOCKS), blk, 0, stream>>>(hwb, dis, cnt, start, epack, b1, aggbuf, sums1);

    // ---- BN1+ReLU fused into layer-2 matmul ----
    mm2_bn_k<<<dim3(nbN), blk, 0, stream>>>(aggbuf, sums1, g1, bt1, W2, hwb);

    // ---- layer 2 (stats into sums2) ----
    gcn_agg<<<dim3(AGG_BLOCKS), blk, 0, stream>>>(hwb, dis, cnt, start, epack, b2, aggbuf, sums2);

    // ---- BN2 + write h + pool ----
    bn_pool<<<dim3(nbN), blk, 0, stream>>>(aggbuf, sums2, g2, bt2, batch, out, pool);
}